// Round 7
// baseline (341.075 us; speedup 1.0000x reference)
//
#include <hip/hip_runtime.h>
#include <hip/hip_bf16.h>
#include <stdint.h>

#define N_NODES 100000
#define N_EDGES 1600000
#define TILE 8192
#define NB 196                                 // 196 buckets: bucket = id>>9
#define BIN_BLOCKS ((N_EDGES + TILE - 1) / TILE)   // 196

// ---- workspace layout (bytes) ----
static const size_t OFF_H      = 0;            // h bf16: 25,600,000
static const size_t OFF_SSCALE = 25600000;     // float 400,000
static const size_t OFF_ROWP   = 26000000;     // int 400,004
static const size_t OFF_RHIST  = 26400016;     // int 1024 (196 used)
static const size_t OFF_SHIST  = 26401040;     // int 1024 (contiguous w/ RHIST for memset)
static const size_t OFF_RBASE  = 26402064;     // int 1024
static const size_t OFF_SBASE  = 26403088;     // int 1024
static const size_t OFF_RCUR   = 26404112;     // int 1024
static const size_t OFF_SCUR   = 26405136;     // int 1024
static const size_t OFF_WFRAG  = 26406160;     // short8 x 2048 = 32,768 (16B aligned)
static const size_t OFF_EBUF   = 26438928;     // uint32 6,400,000
static const size_t OFF_SBUF   = 32838928;     // uint16 3,200,000 -> total ~36.04 MB

using short8 = __attribute__((ext_vector_type(8))) short;
using f32x4  = __attribute__((ext_vector_type(4))) float;

static __device__ __forceinline__ short f2bf(float f) {
    uint32_t u = __float_as_uint(f);
    uint32_t r = (u + 0x7fffu + ((u >> 16) & 1u)) >> 16;
    return (short)r;
}
static __device__ __forceinline__ float bflo(uint32_t u) { return __uint_as_float(u << 16); }
static __device__ __forceinline__ float bfhi(uint32_t u) { return __uint_as_float(u & 0xffff0000u); }

// 0) pre-swizzle W into bf16 MFMA B-fragments (one-time, 2048 threads)
__global__ __launch_bounds__(256) void prep_w_kernel(const float* __restrict__ W,
                                                     short8* __restrict__ wfrag) {
    int slot = blockIdx.x * 256 + threadIdx.x;   // 0..2047
    int f = slot >> 6, lane = slot & 63;
    int quad = lane >> 4, mcol = lane & 15;
    int s = f >> 3, c = f & 7;
    int krow = s * 32 + quad * 8;
    int ncol = c * 16 + mcol;
    short8 wf;
    #pragma unroll
    for (int j = 0; j < 8; j++)
        wf[j] = f2bf(W[(krow + j) * 128 + ncol]);
    wfrag[slot] = wf;
}

// 1) coarse histograms (196 bins each for rcv>>9 and snd>>9), LDS-staged
__global__ __launch_bounds__(256) void hist196_kernel(const int* __restrict__ snd,
                                                      const int* __restrict__ rcv,
                                                      int* __restrict__ rhist,
                                                      int* __restrict__ shist) {
    __shared__ int hr[256], hs[256];
    int t = threadIdx.x;
    hr[t] = 0; hs[t] = 0;
    __syncthreads();
    int base = blockIdx.x * TILE;
    #pragma unroll
    for (int j = 0; j < 32; j++) {
        int idx = base + j * 256 + t;
        if (idx < N_EDGES) {
            atomicAdd(&hr[rcv[idx] >> 9], 1);
            atomicAdd(&hs[snd[idx] >> 9], 1);
        }
    }
    __syncthreads();
    if (t < NB) {
        if (hr[t]) atomicAdd(&rhist[t], hr[t]);
        if (hs[t]) atomicAdd(&shist[t], hs[t]);
    }
}

// 2) scan both 196-bucket histograms -> bases + working cursors
__global__ __launch_bounds__(256) void scanb_kernel(const int* __restrict__ rhist,
                                                    const int* __restrict__ shist,
                                                    int* __restrict__ rbase,
                                                    int* __restrict__ sbase,
                                                    int* __restrict__ rcur,
                                                    int* __restrict__ scur,
                                                    int* __restrict__ row_ptr) {
    __shared__ int s[256];
    int t = threadIdx.x;

    int v = (t < NB) ? rhist[t] : 0;
    s[t] = v;
    __syncthreads();
    #pragma unroll
    for (int off = 1; off < 256; off <<= 1) {
        int tv = (t >= off) ? s[t - off] : 0;
        __syncthreads();
        s[t] += tv;
        __syncthreads();
    }
    if (t < NB) { int e = s[t] - v; rbase[t] = e; rcur[t] = e; }
    __syncthreads();

    v = (t < NB) ? shist[t] : 0;
    s[t] = v;
    __syncthreads();
    #pragma unroll
    for (int off = 1; off < 256; off <<= 1) {
        int tv = (t >= off) ? s[t - off] : 0;
        __syncthreads();
        s[t] += tv;
        __syncthreads();
    }
    if (t < NB) { int e = s[t] - v; sbase[t] = e; scur[t] = e; }
    if (t == 0) row_ptr[N_NODES] = N_EDGES;
}

// 3) fused binning: r-channel packs (snd<<9|rcv&511) -> ebuf grouped by rcv>>9;
//    s-channel packs uint16(snd&511) -> sbuf grouped by snd>>9.
__global__ __launch_bounds__(256) void binr_kernel(const int* __restrict__ snd,
                                                   const int* __restrict__ rcv,
                                                   int* __restrict__ rcur,
                                                   int* __restrict__ scur,
                                                   uint32_t* __restrict__ ebuf,
                                                   uint16_t* __restrict__ sbuf) {
    __shared__ int hist[256];
    __shared__ int coff[256];
    __shared__ int ccur[256];
    __shared__ int gbase[256];
    __shared__ uint32_t stage[TILE];           // 32 KB

    const int t = threadIdx.x;
    const int base = blockIdx.x * TILE;

    uint32_t ss[32], rs[32];
    #pragma unroll
    for (int j = 0; j < 32; j++) {
        int idx = base + j * 256 + t;
        bool ok = idx < N_EDGES;
        ss[j] = ok ? (uint32_t)snd[idx] : 0u;
        rs[j] = ok ? (uint32_t)rcv[idx] : 0xffffffffu;
    }

    // ---------------- r-channel ----------------
    hist[t] = 0;
    __syncthreads();
    #pragma unroll
    for (int j = 0; j < 32; j++)
        if (rs[j] != 0xffffffffu) atomicAdd(&hist[rs[j] >> 9], 1);
    __syncthreads();

    int v = hist[t];
    ccur[t] = v;
    __syncthreads();
    #pragma unroll
    for (int off = 1; off < 256; off <<= 1) {
        int tv = (t >= off) ? ccur[t - off] : 0;
        __syncthreads();
        ccur[t] += tv;
        __syncthreads();
    }
    int excl = ccur[t] - v;
    coff[t] = excl;
    int gb = 0;
    if (v > 0) gb = atomicAdd(&rcur[t], v);
    gbase[t] = gb - excl;
    __syncthreads();
    ccur[t] = excl;
    __syncthreads();

    #pragma unroll
    for (int j = 0; j < 32; j++) {
        uint32_t r = rs[j];
        if (r != 0xffffffffu) {
            int pos = atomicAdd(&ccur[r >> 9], 1);
            stage[pos] = (ss[j] << 9) | (r & 511u);
        }
    }
    __syncthreads();

    int total = coff[255] + hist[255];
    for (int i = t; i < total; i += 256) {
        uint32_t pv = stage[i];
        int lo = 0;
        #pragma unroll
        for (int step = 128; step; step >>= 1)
            if (lo + step < 256 && coff[lo + step] <= i) lo += step;
        ebuf[gbase[lo] + i] = pv;
    }
    __syncthreads();

    // ---------------- s-channel ----------------
    hist[t] = 0;
    __syncthreads();
    #pragma unroll
    for (int j = 0; j < 32; j++)
        if (rs[j] != 0xffffffffu) atomicAdd(&hist[ss[j] >> 9], 1);
    __syncthreads();

    v = hist[t];
    ccur[t] = v;
    __syncthreads();
    #pragma unroll
    for (int off = 1; off < 256; off <<= 1) {
        int tv = (t >= off) ? ccur[t - off] : 0;
        __syncthreads();
        ccur[t] += tv;
        __syncthreads();
    }
    excl = ccur[t] - v;
    coff[t] = excl;
    gb = 0;
    if (v > 0) gb = atomicAdd(&scur[t], v);
    gbase[t] = gb - excl;
    __syncthreads();
    ccur[t] = excl;
    __syncthreads();

    uint16_t* stage16 = (uint16_t*)stage;
    #pragma unroll
    for (int j = 0; j < 32; j++) {
        if (rs[j] != 0xffffffffu) {
            int pos = atomicAdd(&ccur[ss[j] >> 9], 1);
            stage16[pos] = (uint16_t)(ss[j] & 511u);
        }
    }
    __syncthreads();

    total = coff[255] + hist[255];
    for (int i = t; i < total; i += 256) {
        uint16_t pv = stage16[i];
        int lo = 0;
        #pragma unroll
        for (int step = 128; step; step >>= 1)
            if (lo + step < 256 && coff[lo + step] <= i) lo += step;
        sbuf[gbase[lo] + i] = pv;
    }
}

// 4) per-bucket finalize: row_ptr + receiver-sort of senders (now also
//    sender-sorted within each receiver segment, for gather L2 locality)
//    + sender-degree scale.
__global__ __launch_bounds__(256) void bucket_kernel(const int* __restrict__ rbase,
                                                     const int* __restrict__ rhist,
                                                     const int* __restrict__ sbase,
                                                     const int* __restrict__ shist,
                                                     uint32_t* __restrict__ ebuf,
                                                     const uint16_t* __restrict__ sbuf,
                                                     int* __restrict__ row_ptr,
                                                     float* __restrict__ sscale) {
    __shared__ int hist_l[512];
    __shared__ int excl_l[512];
    __shared__ int cur_l[512];
    __shared__ int ps[256];
    __shared__ uint32_t inb[9216];
    __shared__ uint32_t perm[9216];

    const int b = blockIdx.x;
    const int t = threadIdx.x;
    const int nbase = b << 9;
    const int base = rbase[b];
    const int size = rhist[b];

    hist_l[t] = 0; hist_l[t + 256] = 0;
    __syncthreads();

    for (int i = t; i < size; i += 256) {
        uint32_t v = ebuf[base + i];
        inb[i] = v;
        atomicAdd(&hist_l[v & 511u], 1);
    }
    __syncthreads();

    int h0 = hist_l[2 * t], h1 = hist_l[2 * t + 1];
    int p = h0 + h1;
    ps[t] = p;
    __syncthreads();
    #pragma unroll
    for (int off = 1; off < 256; off <<= 1) {
        int tv = (t >= off) ? ps[t - off] : 0;
        __syncthreads();
        ps[t] += tv;
        __syncthreads();
    }
    int pe = ps[t] - p;
    excl_l[2 * t] = pe;
    excl_l[2 * t + 1] = pe + h0;
    cur_l[2 * t] = pe;
    cur_l[2 * t + 1] = pe + h0;
    __syncthreads();

    for (int i = t; i < 512; i += 256) {
        int n = nbase + i;
        if (n < N_NODES) row_ptr[n] = base + excl_l[i];
    }

    for (int i = t; i < size; i += 256) {
        uint32_t v = inb[i];
        int pos = atomicAdd(&cur_l[v & 511u], 1);
        perm[pos] = v >> 9;
    }
    __syncthreads();

    // sender-sort each receiver segment (insertion sort; segments ~16 edges).
    // Gives gather's concurrent waves a monotone sweep over the h table.
    for (int seg = t; seg < 512; seg += 256) {
        int s0 = excl_l[seg];
        int s1 = cur_l[seg];
        for (int i2 = s0 + 1; i2 < s1; i2++) {
            uint32_t key = perm[i2];
            int j = i2 - 1;
            while (j >= s0 && perm[j] > key) { perm[j + 1] = perm[j]; j--; }
            perm[j + 1] = key;
        }
    }
    __syncthreads();

    for (int i = t; i < size; i += 256)
        ebuf[base + i] = perm[i];

    __syncthreads();
    hist_l[t] = 0; hist_l[t + 256] = 0;
    __syncthreads();
    const int sb = sbase[b];
    const int ssz = shist[b];
    for (int i = t; i < ssz; i += 256)
        atomicAdd(&hist_l[(int)sbuf[sb + i]], 1);
    __syncthreads();
    for (int i = t; i < 512; i += 256) {
        int n = nbase + i;
        if (n < N_NODES) sscale[n] = rsqrtf(fmaxf((float)hist_l[i], 1.f));
    }
}

// 5) MFMA GEMM v3: B-fragments straight from global (L2-resident 32 KB)
__global__ __launch_bounds__(256, 3) void gemm_mfma_kernel(const float* __restrict__ x,
                                                           const short8* __restrict__ wfrag,
                                                           const float* __restrict__ bias,
                                                           const float* __restrict__ sscale,
                                                           short* __restrict__ h) {
    const int t = threadIdx.x;
    const int lane = t & 63;
    const int wv = t >> 6;
    const int quad = lane >> 4;
    const int mcol = lane & 15;

    const int node0 = blockIdx.x * 128 + wv * 32;
    short8 afrag[2][4];
    #pragma unroll
    for (int mf = 0; mf < 2; mf++) {
        int node = node0 + mf * 16 + mcol;
        bool ok = node < N_NODES;
        const float* xr = x + (size_t)(ok ? node : 0) * 128;
        #pragma unroll
        for (int s = 0; s < 4; s++) {
            int k0 = s * 32 + quad * 8;
            f32x4 v0 = ok ? *(const f32x4*)(xr + k0)     : f32x4{0.f,0.f,0.f,0.f};
            f32x4 v1 = ok ? *(const f32x4*)(xr + k0 + 4) : f32x4{0.f,0.f,0.f,0.f};
            short8 af;
            #pragma unroll
            for (int j = 0; j < 4; j++) {
                af[j]     = f2bf(v0[j]);
                af[4 + j] = f2bf(v1[j]);
            }
            afrag[mf][s] = af;
        }
    }

    f32x4 acc[2][8];
    #pragma unroll
    for (int mf = 0; mf < 2; mf++)
        #pragma unroll
        for (int c = 0; c < 8; c++)
            acc[mf][c] = f32x4{0.f, 0.f, 0.f, 0.f};

    #pragma unroll
    for (int s = 0; s < 4; s++) {
        #pragma unroll
        for (int c = 0; c < 8; c++) {
            short8 bfrag = wfrag[(s * 8 + c) * 64 + lane];
            acc[0][c] = __builtin_amdgcn_mfma_f32_16x16x32_bf16(afrag[0][s], bfrag, acc[0][c], 0, 0, 0);
            acc[1][c] = __builtin_amdgcn_mfma_f32_16x16x32_bf16(afrag[1][s], bfrag, acc[1][c], 0, 0, 0);
        }
    }

    float rsv[2][4];
    #pragma unroll
    for (int mf = 0; mf < 2; mf++)
        #pragma unroll
        for (int r = 0; r < 4; r++) {
            int nd = node0 + mf * 16 + quad * 4 + r;
            rsv[mf][r] = (nd < N_NODES) ? sscale[nd] : 1.f;
        }

    #pragma unroll
    for (int mf = 0; mf < 2; mf++)
        #pragma unroll
        for (int c = 0; c < 8; c++) {
            float bval = bias[c * 16 + mcol];
            #pragma unroll
            for (int r = 0; r < 4; r++) {
                int nd = node0 + mf * 16 + quad * 4 + r;
                if (nd < N_NODES)
                    h[(size_t)nd * 128 + c * 16 + mcol] =
                        f2bf((acc[mf][c][r] + bval) * rsv[mf][r]);
            }
        }
}

// 6) gather v3: 4 nodes/wave (16 lanes x dwordx4 = one 256B row per quarter),
//    4-deep unroll -> 16 rows in flight per wave; sender-sorted edge lists.
__global__ __launch_bounds__(256) void gather_kernel(const uint4* __restrict__ hrow,
                                                     const int* __restrict__ row_ptr,
                                                     const uint32_t* __restrict__ esrc,
                                                     float4* __restrict__ out4) {
    int wv = threadIdx.x >> 6;
    int lane = threadIdx.x & 63;
    int q = lane >> 4;                 // node slot 0..3
    int ln = lane & 15;                // dim-quarter lane
    int node = blockIdx.x * 16 + wv * 4 + q;

    int b = row_ptr[node];
    int e = row_ptr[node + 1];
    float a0=0.f,a1=0.f,a2=0.f,a3=0.f,a4=0.f,a5=0.f,a6=0.f,a7=0.f;
    int i = b;
    for (; i + 4 <= e; i += 4) {
        uint32_t s0 = esrc[i + 0], s1 = esrc[i + 1], s2 = esrc[i + 2], s3 = esrc[i + 3];
        uint4 v0 = hrow[(size_t)s0 * 16 + ln];
        uint4 v1 = hrow[(size_t)s1 * 16 + ln];
        uint4 v2 = hrow[(size_t)s2 * 16 + ln];
        uint4 v3 = hrow[(size_t)s3 * 16 + ln];
        a0 += bflo(v0.x) + bflo(v1.x) + bflo(v2.x) + bflo(v3.x);
        a1 += bfhi(v0.x) + bfhi(v1.x) + bfhi(v2.x) + bfhi(v3.x);
        a2 += bflo(v0.y) + bflo(v1.y) + bflo(v2.y) + bflo(v3.y);
        a3 += bfhi(v0.y) + bfhi(v1.y) + bfhi(v2.y) + bfhi(v3.y);
        a4 += bflo(v0.z) + bflo(v1.z) + bflo(v2.z) + bflo(v3.z);
        a5 += bfhi(v0.z) + bfhi(v1.z) + bfhi(v2.z) + bfhi(v3.z);
        a6 += bflo(v0.w) + bflo(v1.w) + bflo(v2.w) + bflo(v3.w);
        a7 += bfhi(v0.w) + bfhi(v1.w) + bfhi(v2.w) + bfhi(v3.w);
    }
    for (; i < e; i++) {
        uint32_t s = esrc[i];
        uint4 v = hrow[(size_t)s * 16 + ln];
        a0 += bflo(v.x); a1 += bfhi(v.x);
        a2 += bflo(v.y); a3 += bfhi(v.y);
        a4 += bflo(v.z); a5 += bfhi(v.z);
        a6 += bflo(v.w); a7 += bfhi(v.w);
    }
    float rs = rsqrtf(fmaxf((float)(e - b), 1.f));
    size_t o = (size_t)node * 32 + ln * 2;
    out4[o]     = make_float4(a0 * rs, a1 * rs, a2 * rs, a3 * rs);
    out4[o + 1] = make_float4(a4 * rs, a5 * rs, a6 * rs, a7 * rs);
}

extern "C" void kernel_launch(void* const* d_in, const int* in_sizes, int n_in,
                              void* d_out, int out_size, void* d_ws, size_t ws_size,
                              hipStream_t stream) {
    const float* x    = (const float*)d_in[0];
    const int*   snd  = (const int*)d_in[1];
    const int*   rcv  = (const int*)d_in[2];
    const float* W    = (const float*)d_in[4];
    const float* bias = (const float*)d_in[5];

    char* ws = (char*)d_ws;
    short*    h      = (short*)(ws + OFF_H);
    float*    sscale = (float*)(ws + OFF_SSCALE);
    int*      rowp   = (int*)(ws + OFF_ROWP);
    int*      rhist  = (int*)(ws + OFF_RHIST);
    int*      shist  = (int*)(ws + OFF_SHIST);
    int*      rbase  = (int*)(ws + OFF_RBASE);
    int*      sbase  = (int*)(ws + OFF_SBASE);
    int*      rcur   = (int*)(ws + OFF_RCUR);
    int*      scur   = (int*)(ws + OFF_SCUR);
    short8*   wfrag  = (short8*)(ws + OFF_WFRAG);
    uint32_t* ebuf   = (uint32_t*)(ws + OFF_EBUF);
    uint16_t* sbuf   = (uint16_t*)(ws + OFF_SBUF);

    hipMemsetAsync(ws + OFF_RHIST, 0, 2048, stream);   // rhist + shist

    prep_w_kernel  <<<8, 256, 0, stream>>>(W, wfrag);
    hist196_kernel <<<BIN_BLOCKS, 256, 0, stream>>>(snd, rcv, rhist, shist);
    scanb_kernel   <<<1, 256, 0, stream>>>(rhist, shist, rbase, sbase, rcur, scur, rowp);
    binr_kernel    <<<BIN_BLOCKS, 256, 0, stream>>>(snd, rcv, rcur, scur, ebuf, sbuf);
    bucket_kernel  <<<NB, 256, 0, stream>>>(rbase, rhist, sbase, shist, ebuf, sbuf, rowp, sscale);
    gemm_mfma_kernel<<<(N_NODES + 127) / 128, 256, 0, stream>>>(x, wfrag, bias, sscale, h);
    gather_kernel  <<<N_NODES / 16, 256, 0, stream>>>((const uint4*)h, rowp, ebuf, (float4*)d_out);
}